// Round 9
// baseline (107.902 us; speedup 1.0000x reference)
//
#include <hip/hip_runtime.h>

#define B_ 32
#define N_ 1024
#define NEG 0.01f
#define QSC (1.4426950408889634f/32.0f)   // log2(e)/E folded into staged Wq/bq

using half8  = __attribute__((ext_vector_type(8))) _Float16;
using half4  = __attribute__((ext_vector_type(4))) _Float16;
using half2  = __attribute__((ext_vector_type(2))) _Float16;
using fp16x2 = __attribute__((ext_vector_type(2))) __fp16;
using floatx4 = __attribute__((ext_vector_type(4))) float;

#if defined(__has_builtin)
#if __has_builtin(__builtin_amdgcn_exp2f)
#define EXP2(x) __builtin_amdgcn_exp2f(x)
#endif
#endif
#ifndef EXP2
#define EXP2(x) exp2f(x)
#endif

__device__ inline half2 pkcvt(float a, float b) {
    fp16x2 r = __builtin_amdgcn_cvt_pkrtz(a, b);
    return __builtin_bit_cast(half2, r);
}

__device__ inline half8 cvt8(float4 a, float4 b) {
    half2 p0 = pkcvt(a.x, a.y);
    half2 p1 = pkcvt(a.z, a.w);
    half2 p2 = pkcvt(b.x, b.y);
    half2 p3 = pkcvt(b.z, b.w);
    half8 h = { p0[0],p0[1], p1[0],p1[1], p2[0],p2[1], p3[0],p3[1] };
    return h;
}

// Fully fused: on-the-fly grouped QKV projection + MFMA flash attention +
// 3-layer grouped MFMA MLP. Block = (bg, qtile of 64 q rows) -> grid 1024.
// KT=64 K/V tiles double-buffered (1 barrier/tile). LDS ~27 KB; with
// __launch_bounds__(256,4) -> 4 blocks/CU resident (grid finally big enough).
// xs (MLP input) is written ONLY in the epilogue, so it unions with the whole
// K-loop workspace with no aliasing races (R8 bug fixed).
struct __align__(16) Smem {
    union {
        struct {
            _Float16 Kst[2][64*40];    // ping-pong K tile [kpos][e]
            _Float16 Vtst[2][32*72];   // ping-pong Vt tile [e][kpos]
            union {
                struct { _Float16 wsh[96*36]; float bsh[96]; } wg;  // prologue
                _Float16 qs[64*40];    // projected Q tile (prologue)
            } pq;
        } lp;
        _Float16 xs[64*72];            // MLP input [q][ v(32) | attn(32) ] (epilogue)
    } u;
    float linv[64];
    float bl1[32], bl10[32], bl11[32];
};

__global__ __launch_bounds__(256, 4) void fused_kernel(
    const float* __restrict__ x, const float* __restrict__ w_qkv, const float* __restrict__ b_qkv,
    const float* __restrict__ w_h1,  const float* __restrict__ b_h1,
    const float* __restrict__ w_h10, const float* __restrict__ b_h10,
    const float* __restrict__ w_h11, const float* __restrict__ b_h11,
    float* __restrict__ out)
{
    __shared__ Smem sm;
    int t = threadIdx.x;
    int bg = blockIdx.x >> 4;
    int qtile = blockIdx.x & 15;
    int b = bg >> 1, g = bg & 1;
    int qbase = qtile * 64;
    int lane = t & 63, w = t >> 6;
    int L15 = lane & 15, quad = lane >> 4;

    // ---- stage qkv weights (Q rows pre-scaled by QSC) + biases ----
    for (int idx = t; idx < 96*32; idx += 256) {
        int r = idx >> 5, c = idx & 31;
        float wv = w_qkv[(g*96 + r)*32 + c];
        sm.u.lp.pq.wg.wsh[r*36 + c] = (_Float16)(r < 32 ? wv*QSC : wv);
    }
    if (t < 96) sm.u.lp.pq.wg.bsh[t] = b_qkv[g*96 + t];
    if (t < 32) {
        sm.bl1[t]  = b_h1[g*32+t];
        sm.bl10[t] = b_h10[g*32+t];
        sm.bl11[t] = b_h11[g*32+t];
    }
    __syncthreads();

    // ---- weight B-frags: B[k=i=quad*8+j][n=e=et*16+L15]; bias C-seeds ----
    half8 bwq[2], bwk[2], bwv[2];
    floatx4 cq[2], ck[2], cv[2];
    #pragma unroll
    for (int et = 0; et < 2; et++) {
        bwq[et] = *(const half8*)&sm.u.lp.pq.wg.wsh[(     et*16 + L15)*36 + quad*8];
        bwk[et] = *(const half8*)&sm.u.lp.pq.wg.wsh[(32 + et*16 + L15)*36 + quad*8];
        bwv[et] = *(const half8*)&sm.u.lp.pq.wg.wsh[(64 + et*16 + L15)*36 + quad*8];
        float bq = sm.u.lp.pq.wg.bsh[     et*16 + L15] * QSC;
        float bk = sm.u.lp.pq.wg.bsh[32 + et*16 + L15];
        float bv = sm.u.lp.pq.wg.bsh[64 + et*16 + L15];
        cq[et] = (floatx4){bq,bq,bq,bq};
        ck[et] = (floatx4){bk,bk,bk,bk};
        cv[et] = (floatx4){bv,bv,bv,bv};
    }
    __syncthreads();   // all wsh reads done before qs overwrites the union

    // ---- project Q (wave's own 16 rows) -> qs (wave-private rows) ----
    {
        const float* p = x + ((size_t)b*N_ + qbase + w*16 + L15)*64 + g*32 + quad*8;
        half8 axq = cvt8(*(const float4*)p, *(const float4*)(p + 4));
        floatx4 dq0 = __builtin_amdgcn_mfma_f32_16x16x32_f16(axq, bwq[0], cq[0], 0,0,0);
        floatx4 dq1 = __builtin_amdgcn_mfma_f32_16x16x32_f16(axq, bwq[1], cq[1], 0,0,0);
        #pragma unroll
        for (int r = 0; r < 4; r++) {
            sm.u.lp.pq.qs[(w*16 + quad*4 + r)*40 +      L15] = (_Float16)dq0[r];
            sm.u.lp.pq.qs[(w*16 + quad*4 + r)*40 + 16 + L15] = (_Float16)dq1[r];
        }
    }
    // wave-private LDS rows: same-wave DS ordering suffices, no barrier
    half8 bq = *(const half8*)&sm.u.lp.pq.qs[(w*16 + L15)*40 + quad*8];

    float4 xf0, xf1;
    auto prefetch = [&](int tile) {
        const float* p = x + ((size_t)b*N_ + tile*64 + w*16 + L15)*64 + g*32 + quad*8;
        xf0 = *(const float4*)p;
        xf1 = *(const float4*)(p + 4);
    };
    auto proj_tile = [&](int buf) {
        half8 axk = cvt8(xf0, xf1);
        floatx4 dK[2], dV[2];
        #pragma unroll
        for (int et = 0; et < 2; et++) {
            dK[et] = __builtin_amdgcn_mfma_f32_16x16x32_f16(axk, bwk[et], ck[et], 0,0,0);
            dV[et] = __builtin_amdgcn_mfma_f32_16x16x32_f16(axk, bwv[et], cv[et], 0,0,0);
        }
        int rb = w*16 + quad*4;   // kpos base within the 64-row tile
        #pragma unroll
        for (int et = 0; et < 2; et++) {
            half2 k01 = pkcvt(dK[et][0], dK[et][1]);
            half2 k23 = pkcvt(dK[et][2], dK[et][3]);
            half2 v01 = pkcvt(dV[et][0], dV[et][1]);
            half2 v23 = pkcvt(dV[et][2], dV[et][3]);
            half4 vh = { v01[0], v01[1], v23[0], v23[1] };
            sm.u.lp.Kst[buf][(rb+0)*40 + et*16 + L15] = k01[0];
            sm.u.lp.Kst[buf][(rb+1)*40 + et*16 + L15] = k01[1];
            sm.u.lp.Kst[buf][(rb+2)*40 + et*16 + L15] = k23[0];
            sm.u.lp.Kst[buf][(rb+3)*40 + et*16 + L15] = k23[1];
            *(half4*)&sm.u.lp.Vtst[buf][(et*16 + L15)*72 + rb] = vh;
        }
    };

    // ---- prologue: tile 0 ----
    prefetch(0);
    proj_tile(0);
    __syncthreads();

    floatx4 o0 = {0.f,0.f,0.f,0.f}, o1 = o0;
    float lsum = 0.f;

    for (int kt = 0; kt < 16; kt++) {
        int cur = kt & 1;
        if (kt < 15) prefetch(kt + 1);
        // attention on tile kt (buf cur) — hides prefetch latency
        #pragma unroll
        for (int mt8 = 0; mt8 < 4; mt8++) {
            half8 ak = *(const half8*)&sm.u.lp.Kst[cur][(mt8*16 + L15)*40 + quad*8];
            floatx4 zz = {0.f,0.f,0.f,0.f};
            floatx4 s = __builtin_amdgcn_mfma_f32_16x16x32_f16(ak, bq, zz, 0,0,0);
            float p0 = EXP2(s.x), p1 = EXP2(s.y), p2 = EXP2(s.z), p3 = EXP2(s.w);
            lsum += (p0+p1)+(p2+p3);
            half2 pa = pkcvt(p0, p1);
            half2 pb = pkcvt(p2, p3);
            half4 a0 = { pa[0], pa[1], pb[0], pb[1] };
            half4 bv0 = *(const half4*)&sm.u.lp.Vtst[cur][      L15*72 + mt8*16 + quad*4];
            half4 bv1 = *(const half4*)&sm.u.lp.Vtst[cur][(16 + L15)*72 + mt8*16 + quad*4];
            o0 = __builtin_amdgcn_mfma_f32_16x16x16f16(a0, bv0, o0, 0,0,0);
            o1 = __builtin_amdgcn_mfma_f32_16x16x16f16(a0, bv1, o1, 0,0,0);
        }
        // project tile kt+1 into the other buffer
        if (kt < 15) proj_tile(1 - cur);
        __syncthreads();
    }
    // after final barrier: all lp reads done everywhere -> xs overlay is safe

    // ---- softmax denominators (wave-private linv rows) ----
    lsum += __shfl_xor(lsum, 16, 64); lsum += __shfl_xor(lsum, 32, 64);
    if (quad == 0) sm.linv[w*16 + L15] = 1.0f / lsum;

    // ---- re-project V for own 16 rows -> xs v-part (x rows are L2-hot) ----
    {
        const float* p = x + ((size_t)b*N_ + qbase + w*16 + L15)*64 + g*32 + quad*8;
        half8 axv = cvt8(*(const float4*)p, *(const float4*)(p + 4));
        floatx4 dv0 = __builtin_amdgcn_mfma_f32_16x16x32_f16(axv, bwv[0], cv[0], 0,0,0);
        floatx4 dv1 = __builtin_amdgcn_mfma_f32_16x16x32_f16(axv, bwv[1], cv[1], 0,0,0);
        #pragma unroll
        for (int r = 0; r < 4; r++) {
            sm.u.xs[(w*16 + quad*4 + r)*72 +      L15] = (_Float16)dv0[r];
            sm.u.xs[(w*16 + quad*4 + r)*72 + 16 + L15] = (_Float16)dv1[r];
        }
    }
    // ---- attn part: lane holds O[q=w*16+quad*4+r][e=et*16+L15] ----
    {
        float4 li = *(const float4*)&sm.linv[w*16 + quad*4];
        const floatx4* ofr[2] = { &o0, &o1 };
        #pragma unroll
        for (int et = 0; et < 2; et++) {
            floatx4 ov = *ofr[et];
            sm.u.xs[(w*16+quad*4+0)*72 + 32 + et*16 + L15] = (_Float16)(ov[0]*li.x);
            sm.u.xs[(w*16+quad*4+1)*72 + 32 + et*16 + L15] = (_Float16)(ov[1]*li.y);
            sm.u.xs[(w*16+quad*4+2)*72 + 32 + et*16 + L15] = (_Float16)(ov[2]*li.z);
            sm.u.xs[(w*16+quad*4+3)*72 + 32 + et*16 + L15] = (_Float16)(ov[3]*li.w);
        }
    }
    // xs rows w*16..w*16+15 are wave-private: no barrier needed before MLP reads

    // ---- MLP weight A-frags: A[m=o=mt*16+L15][k=i=quad*4+j] ----
    half4 a1f[2][4], a2f[2][2], a3f[2][2];
    #pragma unroll
    for (int mt = 0; mt < 2; mt++) {
        #pragma unroll
        for (int kt = 0; kt < 4; kt++) {
            float4 f = *(const float4*)(w_h1 + (size_t)(g*32+mt*16+L15)*64 + kt*16 + quad*4);
            half2 ha = pkcvt(f.x, f.y);
            half2 hb = pkcvt(f.z, f.w);
            half4 h = { ha[0], ha[1], hb[0], hb[1] };
            a1f[mt][kt] = h;
        }
        #pragma unroll
        for (int kt = 0; kt < 2; kt++) {
            float4 f = *(const float4*)(w_h10 + (size_t)(g*32+mt*16+L15)*32 + kt*16 + quad*4);
            half2 ha = pkcvt(f.x, f.y);
            half2 hb = pkcvt(f.z, f.w);
            half4 h = { ha[0], ha[1], hb[0], hb[1] };
            a2f[mt][kt] = h;
            float4 f2 = *(const float4*)(w_h11 + (size_t)(g*32+mt*16+L15)*32 + kt*16 + quad*4);
            half2 hc = pkcvt(f2.x, f2.y);
            half2 hd = pkcvt(f2.z, f2.w);
            half4 h2 = { hc[0], hc[1], hd[0], hd[1] };
            a3f[mt][kt] = h2;
        }
    }

    // ---- layer 1 (bias-seeded): D[o][q] over this wave's 16 q rows ----
    floatx4 d1[2];
    #pragma unroll
    for (int mt = 0; mt < 2; mt++) {
        float4 bb = *(const float4*)&sm.bl1[mt*16 + quad*4];
        d1[mt] = (floatx4){ bb.x, bb.y, bb.z, bb.w };
    }
    #pragma unroll
    for (int kt = 0; kt < 4; kt++) {
        half4 b1 = *(const half4*)&sm.u.xs[(w*16+L15)*72 + kt*16 + quad*4];
        d1[0] = __builtin_amdgcn_mfma_f32_16x16x16f16(a1f[0][kt], b1, d1[0], 0,0,0);
        d1[1] = __builtin_amdgcn_mfma_f32_16x16x16f16(a1f[1][kt], b1, d1[1], 0,0,0);
    }
    half4 h1b[2];   // C layout == next layer's B layout: in-register chain
    #pragma unroll
    for (int mt = 0; mt < 2; mt++) {
        float v0 = d1[mt][0]; v0 = (v0>=0.f)?v0:NEG*v0;
        float v1 = d1[mt][1]; v1 = (v1>=0.f)?v1:NEG*v1;
        float v2 = d1[mt][2]; v2 = (v2>=0.f)?v2:NEG*v2;
        float v3 = d1[mt][3]; v3 = (v3>=0.f)?v3:NEG*v3;
        half2 ha = pkcvt(v0, v1);
        half2 hb = pkcvt(v2, v3);
        half4 h = { ha[0], ha[1], hb[0], hb[1] };
        h1b[mt] = h;
    }
    floatx4 d2[2];
    #pragma unroll
    for (int mt = 0; mt < 2; mt++) {
        float4 bb = *(const float4*)&sm.bl10[mt*16 + quad*4];
        d2[mt] = (floatx4){ bb.x, bb.y, bb.z, bb.w };
    }
    #pragma unroll
    for (int mt = 0; mt < 2; mt++)
        #pragma unroll
        for (int kt = 0; kt < 2; kt++)
            d2[mt] = __builtin_amdgcn_mfma_f32_16x16x16f16(a2f[mt][kt], h1b[kt], d2[mt], 0,0,0);
    half4 h2b[2];
    #pragma unroll
    for (int mt = 0; mt < 2; mt++) {
        float v0 = d2[mt][0]; v0 = (v0>=0.f)?v0:NEG*v0;
        float v1 = d2[mt][1]; v1 = (v1>=0.f)?v1:NEG*v1;
        float v2 = d2[mt][2]; v2 = (v2>=0.f)?v2:NEG*v2;
        float v3 = d2[mt][3]; v3 = (v3>=0.f)?v3:NEG*v3;
        half2 ha = pkcvt(v0, v1);
        half2 hb = pkcvt(v2, v3);
        half4 h = { ha[0], ha[1], hb[0], hb[1] };
        h2b[mt] = h;
    }
    floatx4 d3[2];
    #pragma unroll
    for (int mt = 0; mt < 2; mt++) {
        float4 bb = *(const float4*)&sm.bl11[mt*16 + quad*4];
        d3[mt] = (floatx4){ bb.x, bb.y, bb.z, bb.w };
    }
    #pragma unroll
    for (int mt = 0; mt < 2; mt++)
        #pragma unroll
        for (int kt = 0; kt < 2; kt++)
            d3[mt] = __builtin_amdgcn_mfma_f32_16x16x16f16(a3f[mt][kt], h2b[kt], d3[mt], 0,0,0);
    // store: lane holds out[q=qbase+w*16+L15][o=mt*16+quad*4+r] -> float4 per mt
    #pragma unroll
    for (int mt = 0; mt < 2; mt++) {
        float4 ov;
        ov.x = d3[mt][0]; ov.x = (ov.x>=0.f)?ov.x:NEG*ov.x;
        ov.y = d3[mt][1]; ov.y = (ov.y>=0.f)?ov.y:NEG*ov.y;
        ov.z = d3[mt][2]; ov.z = (ov.z>=0.f)?ov.z:NEG*ov.z;
        ov.w = d3[mt][3]; ov.w = (ov.w>=0.f)?ov.w:NEG*ov.w;
        *(float4*)(out + ((size_t)b*N_ + qbase + w*16 + L15)*64 + g*32 + mt*16 + quad*4) = ov;
    }
}

extern "C" void kernel_launch(void* const* d_in, const int* in_sizes, int n_in,
                              void* d_out, int out_size, void* d_ws, size_t ws_size,
                              hipStream_t stream) {
    const float* x_e   = (const float*)d_in[0];
    const float* w_qkv = (const float*)d_in[1];
    const float* b_qkv = (const float*)d_in[2];
    const float* w_h1  = (const float*)d_in[3];
    const float* b_h1  = (const float*)d_in[4];
    const float* w_h10 = (const float*)d_in[5];
    const float* b_h10 = (const float*)d_in[6];
    const float* w_h11 = (const float*)d_in[7];
    const float* b_h11 = (const float*)d_in[8];
    float* out = (float*)d_out;

    hipLaunchKernelGGL(fused_kernel, dim3(B_*2*16), dim3(256), 0, stream,
                       x_e, w_qkv, b_qkv, w_h1, b_h1, w_h10, b_h10, w_h11, b_h11, out);
}